// Round 11
// baseline (45.524 us; speedup 1.0000x reference)
//
#include <hip/hip_runtime.h>
#include <hip/hip_bf16.h>

typedef float f32x4 __attribute__((ext_vector_type(4)));
typedef __bf16 bf16x8 __attribute__((ext_vector_type(8)));
typedef __bf16 bf16x4 __attribute__((ext_vector_type(4)));

#define DEMB 128
#define HIDDEN 64
#define W1T_STRIDE 264   // fallback kernel only

typedef const __attribute__((address_space(1))) void* gas_ptr;
typedef __attribute__((address_space(3))) void* las_ptr;

// ---------------- Phase 1: 32-node (16 KB) tiles, DMA staging, vmcnt(0) ------
// R4 structure with doubled payload per latency round-trip. Per wave-iter:
// 16x global_load_lds (linear, pre-swizzled source), vmcnt(0), two M=16 MFMA
// sub-tiles sharing B-fragments, 4-KB bounce through the stage buffer,
// 64 B/lane linear stores. Only vmcnt(0) waits -> no hand-counted-vmcnt race.
// LDS = 16 KB frags + 4 waves x 16 KB stage = 80 KB -> 2 blocks/CU.
__global__ __launch_bounds__(256) void node_partA_kernel(
    const float* __restrict__ src_embs,
    const float* __restrict__ dst_embs,
    const float* __restrict__ W1,
    __bf16* __restrict__ spart,
    __bf16* __restrict__ dpart,
    int n_tiles32, int blocks_per_table)
{
    __shared__ __bf16 frag_lds[1024 * 8];   // 16 KB: this table's W1 half
    __shared__ float  stage[4][4096];       // 64 KB: 4 waves x 16 KB

    const int table = (blockIdx.x >= blocks_per_table) ? 1 : 0;
    const int bid = blockIdx.x - table * blocks_per_table;
    const float* __restrict__ E = table ? dst_embs : src_embs;
    __bf16* __restrict__ P = table ? dpart : spart;
    const int kofs = table * 128;

    // Stage this table's W1 half into fragment-ordered LDS (R3/R4-proven).
    for (int cid = threadIdx.x; cid < 1024; cid += 256) {
        const int el = cid & 15;
        const int gk = (cid >> 4) & 3;
        const int kk = (cid >> 6) & 3;
        const int t  = (cid >> 8) & 3;
        const int kbase = kofs + kk * 32 + gk * 8;
        bf16x8 ch;
#pragma unroll
        for (int j = 0; j < 8; ++j)
            ch[j] = (__bf16)W1[(kbase + j) * HIDDEN + 4 * el + t];
        *reinterpret_cast<bf16x8*>(&frag_lds[cid * 8]) = ch;
    }
    __syncthreads();

    const int lane = threadIdx.x & 63;
    const int el = lane & 15;
    const int gk = lane >> 4;
    const int wid = threadIdx.x >> 6;
    char* awc = (char*)&stage[wid][0];

    // Pre-swizzled global source (XOR row-bits 9-11 into 16B-slot bits 4-6);
    // read side applies the same involution -> linear LDS dest stays valid.
    int soff[16];
#pragma unroll
    for (int op = 0; op < 16; ++op) {
        const int d = op * 1024 + lane * 16;
        soff[op] = d ^ (((d >> 9) & 7) << 4);
    }
    const int ab0 = (el * 512 + gk * 32) ^ ((el & 7) << 4);  // sub-tile h adds h*8192

    const int tstride = blocks_per_table * 4;
    for (int tile = bid * 4 + wid; tile < n_tiles32; tile += tstride) {
        const char* ebase = (const char*)E + (size_t)tile * 16384;
#pragma unroll
        for (int op = 0; op < 16; ++op)
            __builtin_amdgcn_global_load_lds((gas_ptr)(ebase + soff[op]),
                                             (las_ptr)(awc + op * 1024), 16, 0, 0);
        asm volatile("s_waitcnt vmcnt(0)" ::: "memory");

        f32x4 acc[8] = {{0.f,0.f,0.f,0.f},{0.f,0.f,0.f,0.f},{0.f,0.f,0.f,0.f},
                        {0.f,0.f,0.f,0.f},{0.f,0.f,0.f,0.f},{0.f,0.f,0.f,0.f},
                        {0.f,0.f,0.f,0.f},{0.f,0.f,0.f,0.f}};
#pragma unroll
        for (int kk = 0; kk < 4; ++kk) {
            const int abL = ab0 + kk * 128;
            f32x4 l0 = *reinterpret_cast<const f32x4*>(awc + abL);
            f32x4 l1 = *reinterpret_cast<const f32x4*>(awc + (abL ^ 16));
            f32x4 h0 = *reinterpret_cast<const f32x4*>(awc + 8192 + abL);
            f32x4 h1 = *reinterpret_cast<const f32x4*>(awc + 8192 + (abL ^ 16));
            bf16x8 alo, ahi;
#pragma unroll
            for (int j = 0; j < 4; ++j) {
                alo[j] = (__bf16)l0[j]; alo[4 + j] = (__bf16)l1[j];
                ahi[j] = (__bf16)h0[j]; ahi[4 + j] = (__bf16)h1[j];
            }
#pragma unroll
            for (int t = 0; t < 4; ++t) {
                const bf16x8 b = *reinterpret_cast<const bf16x8*>(
                    &frag_lds[(size_t)((t * 4 + kk) * 4 + gk) * 128 + el * 8]);
                acc[t]     = __builtin_amdgcn_mfma_f32_16x16x32_bf16(alo, b, acc[t], 0, 0, 0);
                acc[4 + t] = __builtin_amdgcn_mfma_f32_16x16x32_bf16(ahi, b, acc[4 + t], 0, 0, 0);
            }
        }

        // All ds_reads drained before overwriting the stage buffer with output.
        asm volatile("s_waitcnt lgkmcnt(0)" ::: "memory");
        __builtin_amdgcn_sched_barrier(0);

        // Bounce 32x64 bf16 (4 KB) output tile; unit 4*el+t at row h*16+gk*4+r.
#pragma unroll
        for (int h = 0; h < 2; ++h)
#pragma unroll
            for (int r = 0; r < 4; ++r) {
                bf16x4 pk;
#pragma unroll
                for (int t = 0; t < 4; ++t) pk[t] = (__bf16)acc[h * 4 + t][r];
                *reinterpret_cast<bf16x4*>(
                    awc + (h * 16 + gk * 4 + r) * 128 + el * 8) = pk;
            }
        asm volatile("s_waitcnt lgkmcnt(0)" ::: "memory");
        __builtin_amdgcn_sched_barrier(0);

        // Linear copy-out: 64 lanes x 64 B = 4 KB contiguous -> full-line writes.
        char* pb = (char*)P + (size_t)tile * 4096;
#pragma unroll
        for (int i = 0; i < 4; ++i) {
            f32x4 c = *reinterpret_cast<const f32x4*>(awc + lane * 64 + i * 16);
            *reinterpret_cast<f32x4*>(pb + lane * 64 + i * 16) = c;
        }
    }
}

// ---------------- Phase 2: per-edge gather of bf16 partials + MLP tail --------
__global__ __launch_bounds__(256, 8) void edge_tail2_kernel(
    const __bf16* __restrict__ spart,
    const __bf16* __restrict__ dpart,
    const int* __restrict__ src_ids,
    const int* __restrict__ dst_ids,
    const float* __restrict__ b1,
    const float* __restrict__ W2,
    const float* __restrict__ b2,
    float* __restrict__ out,
    int n_edges)
{
    const int lane = threadIdx.x & 63;
    const int c = lane & 7;
    float b1v[8], w2v[8];
#pragma unroll
    for (int j = 0; j < 8; ++j) { b1v[j] = b1[c * 8 + j]; w2v[j] = W2[c * 8 + j]; }
    const float bias2 = b2[0];

    int gid = (blockIdx.x * blockDim.x + threadIdx.x) >> 3;
    const int gstride = (gridDim.x * blockDim.x) >> 3;

    for (int e = gid; e < n_edges; e += gstride) {
        const long long sid = src_ids[e];
        const long long did = dst_ids[e];
        const bf16x8 s8 = *reinterpret_cast<const bf16x8*>(spart + sid * HIDDEN + c * 8);
        const bf16x8 d8 = *reinterpret_cast<const bf16x8*>(dpart + did * HIDDEN + c * 8);
        float v = 0.f;
#pragma unroll
        for (int j = 0; j < 8; ++j) {
            float h = (float)s8[j] + (float)d8[j] + b1v[j];
            h = fmaxf(h, 0.f);
            v = fmaf(h, w2v[j], v);
        }
        v += __shfl_xor(v, 1, 64);
        v += __shfl_xor(v, 2, 64);
        v += __shfl_xor(v, 4, 64);
        if (c == 0) out[e] = v + bias2;
    }
}

// ---------------- Fallback (round-1 proven kernel) if ws too small ------------
__global__ __launch_bounds__(256) void edge_mlp_kernel(
    const float* __restrict__ src_embs,
    const float* __restrict__ dst_embs,
    const int* __restrict__ src_ids,
    const int* __restrict__ dst_ids,
    const float* __restrict__ W1,
    const float* __restrict__ b1,
    const float* __restrict__ W2,
    const float* __restrict__ b2,
    float* __restrict__ out,
    int n_edges, int n_groups)
{
    __shared__ __bf16 w1t[64 * W1T_STRIDE];
    for (int s = threadIdx.x; s < 256 * 64; s += 256) {
        int k = s >> 6;
        int n = s & 63;
        w1t[n * W1T_STRIDE + k] = (__bf16)W1[s];
    }
    __syncthreads();

    const int lane = threadIdx.x & 63;
    const int el = lane & 15;
    const int gk = lane >> 4;

    float b1v[4], w2v[4];
#pragma unroll
    for (int t = 0; t < 4; ++t) { b1v[t] = b1[16 * t + el]; w2v[t] = W2[16 * t + el]; }
    const float bias2 = b2[0];

    const int gw0 = blockIdx.x * 4 + (threadIdx.x >> 6);
    const int gstride = gridDim.x * 4;

    for (int g = gw0; g < n_groups; g += gstride) {
        const int e_base = g * 16;
        int e = e_base + el;
        if (e >= n_edges) e = n_edges - 1;
        const long long sid = src_ids[e];
        const long long did = dst_ids[e];
        const float* sp = src_embs + sid * DEMB + gk * 8;
        const float* dp = dst_embs + did * DEMB + gk * 8;

        f32x4 acc[4] = {{0.f,0.f,0.f,0.f},{0.f,0.f,0.f,0.f},
                        {0.f,0.f,0.f,0.f},{0.f,0.f,0.f,0.f}};
#pragma unroll
        for (int kk = 0; kk < 8; ++kk) {
            const float* ap = (kk < 4) ? (sp + kk * 32) : (dp + (kk - 4) * 32);
            f32x4 f0 = *reinterpret_cast<const f32x4*>(ap);
            f32x4 f1 = *reinterpret_cast<const f32x4*>(ap + 4);
            bf16x8 a;
#pragma unroll
            for (int j = 0; j < 4; ++j) { a[j] = (__bf16)f0[j]; a[4+j] = (__bf16)f1[j]; }
#pragma unroll
            for (int t = 0; t < 4; ++t) {
                const bf16x8 bfrag = *reinterpret_cast<const bf16x8*>(
                    &w1t[(16 * t + el) * W1T_STRIDE + kk * 32 + gk * 8]);
                acc[t] = __builtin_amdgcn_mfma_f32_16x16x32_bf16(a, bfrag, acc[t], 0, 0, 0);
            }
        }
        float s0[4];
#pragma unroll
        for (int r = 0; r < 4; ++r) {
            float v = 0.f;
#pragma unroll
            for (int t = 0; t < 4; ++t) {
                float h = acc[t][r] + b1v[t];
                h = fmaxf(h, 0.f);
                v = fmaf(h, w2v[t], v);
            }
#pragma unroll
            for (int m = 1; m < 16; m <<= 1) v += __shfl_xor(v, m, 64);
            s0[r] = v + bias2;
        }
        const int row0 = e_base + gk * 4;
        if (el == 0) {
            if (row0 + 4 <= n_edges) {
                f32x4 o = {s0[0], s0[1], s0[2], s0[3]};
                *reinterpret_cast<f32x4*>(out + row0) = o;
            } else {
#pragma unroll
                for (int r = 0; r < 4; ++r)
                    if (row0 + r < n_edges) out[row0 + r] = s0[r];
            }
        }
    }
}

extern "C" void kernel_launch(void* const* d_in, const int* in_sizes, int n_in,
                              void* d_out, int out_size, void* d_ws, size_t ws_size,
                              hipStream_t stream) {
    const float* src_embs = (const float*)d_in[0];
    const float* dst_embs = (const float*)d_in[1];
    const int*   src_ids  = (const int*)d_in[2];
    const int*   dst_ids  = (const int*)d_in[3];
    const float* W1 = (const float*)d_in[4];
    const float* b1 = (const float*)d_in[5];
    const float* W2 = (const float*)d_in[6];
    const float* b2 = (const float*)d_in[7];
    float* out = (float*)d_out;

    const int n_edges = in_sizes[2];
    const int n_nodes = in_sizes[0] / DEMB;                   // 100000
    const size_t part_elems = (size_t)n_nodes * HIDDEN;
    const size_t need = 2 * part_elems * sizeof(__bf16);      // 25.6 MB

    if (ws_size >= need && (n_nodes % 32) == 0) {
        __bf16* spart = (__bf16*)d_ws;
        __bf16* dpart = spart + part_elems;
        const int n_tiles32 = n_nodes / 32;                   // 3125

        // 256 blocks/table = 512 total = 2 blocks/CU (80 KB LDS), ~3 tiles/wave.
        int bpt = 256;
        if (bpt * 4 > n_tiles32) bpt = (n_tiles32 + 3) / 4;
        node_partA_kernel<<<2 * bpt, 256, 0, stream>>>(
            src_embs, dst_embs, W1, spart, dpart, n_tiles32, bpt);

        // Single pass: one edge per 8-lane group, max gather parallelism.
        int blocks2 = (n_edges + 31) / 32;                    // 9375
        edge_tail2_kernel<<<blocks2, 256, 0, stream>>>(
            spart, dpart, src_ids, dst_ids, b1, W2, b2, out, n_edges);
    } else {
        const int n_groups = (n_edges + 15) / 16;
        int blocks = (n_groups + 3) / 4;
        if (blocks > 1024) blocks = 1024;
        edge_mlp_kernel<<<blocks, 256, 0, stream>>>(
            src_embs, dst_embs, src_ids, dst_ids, W1, b1, W2, b2, out,
            n_edges, n_groups);
    }
}

// Round 12
// 44.423 us; speedup vs baseline: 1.0248x; 1.0248x over previous
//
#include <hip/hip_runtime.h>
#include <hip/hip_bf16.h>

typedef float f32x4 __attribute__((ext_vector_type(4)));
typedef __bf16 bf16x8 __attribute__((ext_vector_type(8)));
typedef __bf16 bf16x4 __attribute__((ext_vector_type(4)));

#define DEMB 128
#define HIDDEN 64
#define W1T_STRIDE 264   // fallback kernel only

// ---------------- Phase 1: depth-2 (triple-buffer) reg prefetch --------------
// R4's 2-launch shape + R10's sched_barrier-pinned reg pipeline, deepened to
// depth-2: loads for tiles t+s and t+2s are in flight while computing tile t.
// Hand-unrolled 3-phase rotation (static reg indices). Compiler-managed
// waitcnt only (no hand vmcnt -> no race). W1 half staged in-block into
// fragment-ordered LDS; output bounced through LDS for full-line writes.
__global__ void node_partB_kernel(
    const float* __restrict__ src_embs,
    const float* __restrict__ dst_embs,
    const float* __restrict__ W1,
    __bf16* __restrict__ spart,
    __bf16* __restrict__ dpart,
    int n_tiles, int blocks_per_table)
{
    __shared__ __bf16 frag_lds[1024 * 8];   // 16 KB: this table's W1 half
    __shared__ float  bounce[4][512];       // 8 KB: 4 waves x 2 KB

    const int table = (blockIdx.x >= blocks_per_table) ? 1 : 0;
    const int bid = blockIdx.x - table * blocks_per_table;
    const float* __restrict__ E = table ? dst_embs : src_embs;
    __bf16* __restrict__ P = table ? dpart : spart;
    const int kofs = table * 128;

    // Stage this table's W1 half into fragment-ordered LDS (R3/R4-proven).
    for (int cid = threadIdx.x; cid < 1024; cid += 256) {
        const int el = cid & 15;
        const int gk = (cid >> 4) & 3;
        const int kk = (cid >> 6) & 3;
        const int t  = (cid >> 8) & 3;
        const int kbase = kofs + kk * 32 + gk * 8;
        bf16x8 ch;
#pragma unroll
        for (int j = 0; j < 8; ++j)
            ch[j] = (__bf16)W1[(kbase + j) * HIDDEN + 4 * el + t];
        *reinterpret_cast<bf16x8*>(&frag_lds[cid * 8]) = ch;
    }
    __syncthreads();

    const int lane = threadIdx.x & 63;
    const int el = lane & 15;
    const int gk = lane >> 4;
    const int wid = threadIdx.x >> 6;
    char* obc = (char*)&bounce[wid][0];

    const int ts = blocks_per_table * 4;    // tile stride
    int tile = bid * 4 + wid;
    if (tile >= n_tiles) return;

    f32x4 Ra[8], Rb[8], Rc[8];

#define LOADT(T, R)                                                          \
    do {                                                                     \
        int tc_ = (T); if (tc_ >= n_tiles) tc_ = n_tiles - 1;                \
        const float* rp_ = E + (size_t)tc_ * 2048 + el * 128 + gk * 8;       \
        _Pragma("unroll")                                                    \
        for (int kk = 0; kk < 4; ++kk) {                                     \
            (R)[2 * kk]     = *reinterpret_cast<const f32x4*>(rp_ + kk * 32);\
            (R)[2 * kk + 1] = *reinterpret_cast<const f32x4*>(rp_ + kk * 32 + 4);\
        }                                                                    \
    } while (0)

#define COMPUTE_STORE(T, R)                                                  \
    do {                                                                     \
        f32x4 acc[4] = {{0.f,0.f,0.f,0.f},{0.f,0.f,0.f,0.f},                 \
                        {0.f,0.f,0.f,0.f},{0.f,0.f,0.f,0.f}};                \
        _Pragma("unroll")                                                    \
        for (int kk = 0; kk < 4; ++kk) {                                     \
            bf16x8 a;                                                        \
            _Pragma("unroll")                                                \
            for (int j = 0; j < 4; ++j) {                                    \
                a[j]     = (__bf16)(R)[2 * kk][j];                           \
                a[4 + j] = (__bf16)(R)[2 * kk + 1][j];                       \
            }                                                                \
            _Pragma("unroll")                                                \
            for (int t = 0; t < 4; ++t) {                                    \
                const bf16x8 b = *reinterpret_cast<const bf16x8*>(           \
                    &frag_lds[(size_t)((t * 4 + kk) * 4 + gk) * 128 + el * 8]);\
                acc[t] = __builtin_amdgcn_mfma_f32_16x16x32_bf16(a, b, acc[t], 0, 0, 0);\
            }                                                                \
        }                                                                    \
        _Pragma("unroll")                                                    \
        for (int r = 0; r < 4; ++r) {                                        \
            bf16x4 pk;                                                       \
            _Pragma("unroll")                                                \
            for (int t = 0; t < 4; ++t) pk[t] = (__bf16)acc[t][r];           \
            *reinterpret_cast<bf16x4*>(obc + (gk * 4 + r) * 128 + el * 8) = pk;\
        }                                                                    \
        asm volatile("s_waitcnt lgkmcnt(0)" ::: "memory");                   \
        __builtin_amdgcn_sched_barrier(0);                                   \
        f32x4 c0 = *reinterpret_cast<const f32x4*>(obc + lane * 32);         \
        f32x4 c1 = *reinterpret_cast<const f32x4*>(obc + lane * 32 + 16);    \
        char* pb = (char*)P + (size_t)(T) * 2048;                            \
        *reinterpret_cast<f32x4*>(pb + lane * 32) = c0;                      \
        *reinterpret_cast<f32x4*>(pb + lane * 32 + 16) = c1;                 \
    } while (0)

    // Prologue: depth-2.
    LOADT(tile, Ra);
    LOADT(tile + ts, Rb);

    while (true) {
        // phase A: compute Ra, prefetch into Rc
        LOADT(tile + 2 * ts, Rc);
        __builtin_amdgcn_sched_barrier(0);
        COMPUTE_STORE(tile, Ra);
        tile += ts; if (tile >= n_tiles) break;

        // phase B: compute Rb, prefetch into Ra
        LOADT(tile + 2 * ts, Ra);
        __builtin_amdgcn_sched_barrier(0);
        COMPUTE_STORE(tile, Rb);
        tile += ts; if (tile >= n_tiles) break;

        // phase C: compute Rc, prefetch into Rb
        LOADT(tile + 2 * ts, Rb);
        __builtin_amdgcn_sched_barrier(0);
        COMPUTE_STORE(tile, Rc);
        tile += ts; if (tile >= n_tiles) break;
    }
#undef LOADT
#undef COMPUTE_STORE
}

// ---------------- Phase 2: per-edge gather of bf16 partials + MLP tail --------
__global__ __launch_bounds__(256, 8) void edge_tail2_kernel(
    const __bf16* __restrict__ spart,
    const __bf16* __restrict__ dpart,
    const int* __restrict__ src_ids,
    const int* __restrict__ dst_ids,
    const float* __restrict__ b1,
    const float* __restrict__ W2,
    const float* __restrict__ b2,
    float* __restrict__ out,
    int n_edges)
{
    const int lane = threadIdx.x & 63;
    const int c = lane & 7;
    float b1v[8], w2v[8];
#pragma unroll
    for (int j = 0; j < 8; ++j) { b1v[j] = b1[c * 8 + j]; w2v[j] = W2[c * 8 + j]; }
    const float bias2 = b2[0];

    int gid = (blockIdx.x * blockDim.x + threadIdx.x) >> 3;
    const int gstride = (gridDim.x * blockDim.x) >> 3;

    for (int e = gid; e < n_edges; e += gstride) {
        const long long sid = src_ids[e];
        const long long did = dst_ids[e];
        const bf16x8 s8 = *reinterpret_cast<const bf16x8*>(spart + sid * HIDDEN + c * 8);
        const bf16x8 d8 = *reinterpret_cast<const bf16x8*>(dpart + did * HIDDEN + c * 8);
        float v = 0.f;
#pragma unroll
        for (int j = 0; j < 8; ++j) {
            float h = (float)s8[j] + (float)d8[j] + b1v[j];
            h = fmaxf(h, 0.f);
            v = fmaf(h, w2v[j], v);
        }
        v += __shfl_xor(v, 1, 64);
        v += __shfl_xor(v, 2, 64);
        v += __shfl_xor(v, 4, 64);
        if (c == 0) out[e] = v + bias2;
    }
}

// ---------------- Fallback (round-1 proven kernel) if ws too small ------------
__global__ __launch_bounds__(256) void edge_mlp_kernel(
    const float* __restrict__ src_embs,
    const float* __restrict__ dst_embs,
    const int* __restrict__ src_ids,
    const int* __restrict__ dst_ids,
    const float* __restrict__ W1,
    const float* __restrict__ b1,
    const float* __restrict__ W2,
    const float* __restrict__ b2,
    float* __restrict__ out,
    int n_edges, int n_groups)
{
    __shared__ __bf16 w1t[64 * W1T_STRIDE];
    for (int s = threadIdx.x; s < 256 * 64; s += 256) {
        int k = s >> 6;
        int n = s & 63;
        w1t[n * W1T_STRIDE + k] = (__bf16)W1[s];
    }
    __syncthreads();

    const int lane = threadIdx.x & 63;
    const int el = lane & 15;
    const int gk = lane >> 4;

    float b1v[4], w2v[4];
#pragma unroll
    for (int t = 0; t < 4; ++t) { b1v[t] = b1[16 * t + el]; w2v[t] = W2[16 * t + el]; }
    const float bias2 = b2[0];

    const int gw0 = blockIdx.x * 4 + (threadIdx.x >> 6);
    const int gstride = gridDim.x * 4;

    for (int g = gw0; g < n_groups; g += gstride) {
        const int e_base = g * 16;
        int e = e_base + el;
        if (e >= n_edges) e = n_edges - 1;
        const long long sid = src_ids[e];
        const long long did = dst_ids[e];
        const float* sp = src_embs + sid * DEMB + gk * 8;
        const float* dp = dst_embs + did * DEMB + gk * 8;

        f32x4 acc[4] = {{0.f,0.f,0.f,0.f},{0.f,0.f,0.f,0.f},
                        {0.f,0.f,0.f,0.f},{0.f,0.f,0.f,0.f}};
#pragma unroll
        for (int kk = 0; kk < 8; ++kk) {
            const float* ap = (kk < 4) ? (sp + kk * 32) : (dp + (kk - 4) * 32);
            f32x4 f0 = *reinterpret_cast<const f32x4*>(ap);
            f32x4 f1 = *reinterpret_cast<const f32x4*>(ap + 4);
            bf16x8 a;
#pragma unroll
            for (int j = 0; j < 4; ++j) { a[j] = (__bf16)f0[j]; a[4+j] = (__bf16)f1[j]; }
#pragma unroll
            for (int t = 0; t < 4; ++t) {
                const bf16x8 bfrag = *reinterpret_cast<const bf16x8*>(
                    &w1t[(16 * t + el) * W1T_STRIDE + kk * 32 + gk * 8]);
                acc[t] = __builtin_amdgcn_mfma_f32_16x16x32_bf16(a, bfrag, acc[t], 0, 0, 0);
            }
        }
        float s0[4];
#pragma unroll
        for (int r = 0; r < 4; ++r) {
            float v = 0.f;
#pragma unroll
            for (int t = 0; t < 4; ++t) {
                float h = acc[t][r] + b1v[t];
                h = fmaxf(h, 0.f);
                v = fmaf(h, w2v[t], v);
            }
#pragma unroll
            for (int m = 1; m < 16; m <<= 1) v += __shfl_xor(v, m, 64);
            s0[r] = v + bias2;
        }
        const int row0 = e_base + gk * 4;
        if (el == 0) {
            if (row0 + 4 <= n_edges) {
                f32x4 o = {s0[0], s0[1], s0[2], s0[3]};
                *reinterpret_cast<f32x4*>(out + row0) = o;
            } else {
#pragma unroll
                for (int r = 0; r < 4; ++r)
                    if (row0 + r < n_edges) out[row0 + r] = s0[r];
            }
        }
    }
}

extern "C" void kernel_launch(void* const* d_in, const int* in_sizes, int n_in,
                              void* d_out, int out_size, void* d_ws, size_t ws_size,
                              hipStream_t stream) {
    const float* src_embs = (const float*)d_in[0];
    const float* dst_embs = (const float*)d_in[1];
    const int*   src_ids  = (const int*)d_in[2];
    const int*   dst_ids  = (const int*)d_in[3];
    const float* W1 = (const float*)d_in[4];
    const float* b1 = (const float*)d_in[5];
    const float* W2 = (const float*)d_in[6];
    const float* b2 = (const float*)d_in[7];
    float* out = (float*)d_out;

    const int n_edges = in_sizes[2];
    const int n_nodes = in_sizes[0] / DEMB;                   // 100000
    const size_t part_elems = (size_t)n_nodes * HIDDEN;
    const size_t need = 2 * part_elems * sizeof(__bf16);      // 25.6 MB

    if (ws_size >= need && (n_nodes % 16) == 0) {
        __bf16* spart = (__bf16*)d_ws;
        __bf16* dpart = spart + part_elems;
        const int n_tiles = n_nodes / 16;                     // 6250

        // 256 blocks/table = 512 total; 1024 waves/table -> ~6 tiles/wave so the
        // depth-2 pipeline has a steady state. No launch_bounds cap (VGPR ~150).
        int bpt = 256;
        if (bpt * 4 > n_tiles) bpt = (n_tiles + 3) / 4;
        node_partB_kernel<<<2 * bpt, 256, 0, stream>>>(
            src_embs, dst_embs, W1, spart, dpart, n_tiles, bpt);

        int blocks2 = (n_edges + 31) / 32;
        if (blocks2 > 2048) blocks2 = 2048;
        edge_tail2_kernel<<<blocks2, 256, 0, stream>>>(
            spart, dpart, src_ids, dst_ids, b1, W2, b2, out, n_edges);
    } else {
        const int n_groups = (n_edges + 15) / 16;
        int blocks = (n_groups + 3) / 4;
        if (blocks > 1024) blocks = 1024;
        edge_mlp_kernel<<<blocks, 256, 0, stream>>>(
            src_embs, dst_embs, src_ids, dst_ids, W1, b1, W2, b2, out,
            n_edges, n_groups);
    }
}